// Round 1
// baseline (379.693 us; speedup 1.0000x reference)
//
#include <hip/hip_runtime.h>

// ---------------------------------------------------------------------------
// Fused LeNet forward (with the reference's "buggy" stride-1 top-left maxpool).
// Key exploit: pool keeps only top-left region, so conv1 only needs 15x15
// output positions (input rows/cols 0..18) and conv2 only needs 6x6 positions.
//
// One block = 256 threads = 4 waves; wave w fully processes image
// blockIdx.x*4 + w. All intermediates live in LDS (union-reused buffers).
// fp32 throughout (threshold 4.9e-2, we land ~1e-5).
// ---------------------------------------------------------------------------

constexpr int THREADS = 256;
constexpr int IMGS_PER_BLOCK = 4;

// LDS float offsets
constexpr int W1_OFF = 0;          // conv1 weights: 6*3*5*5 = 450
constexpr int W2_OFF = 450;        // conv2 weights: 16*6*5*5 = 2400
constexpr int IMG_BASE = 2852;     // round 2850 up to multiple of 4 (float4 align)
constexpr int IMG_STRIDE = 2528;   // per-image LDS floats (multiple of 4)
// per-image layout:
//   bufA @ +0    : xs [3][19][19] = 1083   then  p1 [6][14][14] = 1176
//   bufB @ +1176 : c1 [6][15][15] = 1350   then  c2 [16][6][6]=576 | p2 @+576 (400)
//                                                 | fc1o @+976 (120) | fc2o @+1096 (84)
constexpr int BUFB = 1176;
constexpr int LDS_FLOATS = IMG_BASE + IMGS_PER_BLOCK * IMG_STRIDE; // 12964 -> 51856 B

extern "C" __global__ __launch_bounds__(THREADS, 3)
void lenet_fused(const float* __restrict__ x,
                 const float* __restrict__ w1,
                 const float* __restrict__ w2,
                 const float* __restrict__ fc1w, const float* __restrict__ fc1b,
                 const float* __restrict__ fc2w, const float* __restrict__ fc2b,
                 const float* __restrict__ fc3w, const float* __restrict__ fc3b,
                 float* __restrict__ out)
{
    __shared__ __align__(16) float lds[LDS_FLOATS];
    const int tid  = threadIdx.x;
    const int lane = tid & 63;
    const int wv   = tid >> 6;
    const int img  = blockIdx.x * IMGS_PER_BLOCK + wv;

    // ---- stage 0: stage conv weights (block-wide) + input patch (per wave) ----
    for (int i = tid; i < 450;  i += THREADS) lds[W1_OFF + i] = w1[i];
    for (int i = tid; i < 2400; i += THREADS) lds[W2_OFF + i] = w2[i];

    float* base = &lds[IMG_BASE + wv * IMG_STRIDE];
    float* xs = base;                       // [3][19][19]
    const float* xg = x + (size_t)img * 3072;
    for (int i = lane; i < 1083; i += 64) {
        int c = i / 361, rem = i - c * 361;
        int r = rem / 19, cl = rem - r * 19;
        xs[i] = xg[c * 1024 + r * 32 + cl];
    }
    __syncthreads();

    // ---- stage 1: conv1 + relu -> c1 [6][15][15] ----
    // strip = (oc, row): 90 strips, each computes 15 output cols in registers.
    float* c1 = base + BUFB;
    const float* w1s = &lds[W1_OFF];
    for (int s = lane; s < 90; s += 64) {
        int oc = s / 15, r = s - oc * 15;
        float acc[15];
        #pragma unroll
        for (int c = 0; c < 15; ++c) acc[c] = 0.f;
        for (int ci = 0; ci < 3; ++ci) {
            #pragma unroll
            for (int kr = 0; kr < 5; ++kr) {
                const float* xrow = xs + ci * 361 + (r + kr) * 19;
                float xv[19];
                #pragma unroll
                for (int j = 0; j < 19; ++j) xv[j] = xrow[j];
                const float* wr = w1s + oc * 75 + ci * 25 + kr * 5;
                float wk[5];
                #pragma unroll
                for (int j = 0; j < 5; ++j) wk[j] = wr[j];
                #pragma unroll
                for (int kc = 0; kc < 5; ++kc)
                    #pragma unroll
                    for (int c = 0; c < 15; ++c)
                        acc[c] += xv[c + kc] * wk[kc];
            }
        }
        #pragma unroll
        for (int c = 0; c < 15; ++c)
            c1[oc * 225 + r * 15 + c] = fmaxf(acc[c], 0.f);
    }
    __syncthreads();

    // ---- stage 2: buggy pool1 -> p1 [6][14][14] (overwrites xs region) ----
    float* p1 = base;
    for (int o = lane; o < 1176; o += 64) {
        int oc = o / 196, rem = o - oc * 196;
        int r = rem / 14, c = rem - r * 14;
        const float* b0 = c1 + oc * 225 + r * 15 + c;
        p1[o] = fmaxf(fmaxf(b0[0], b0[1]), fmaxf(b0[15], b0[16]));
    }
    __syncthreads();

    // ---- stage 3: conv2 + relu -> c2 [16][6][6] (only top-left 6x6 needed) ----
    float* c2 = base + BUFB;
    const float* w2s = &lds[W2_OFF];
    for (int s = lane; s < 96; s += 64) {
        int oc = s / 6, r = s - oc * 6;
        float acc[6];
        #pragma unroll
        for (int c = 0; c < 6; ++c) acc[c] = 0.f;
        for (int ci = 0; ci < 6; ++ci) {
            #pragma unroll
            for (int kr = 0; kr < 5; ++kr) {
                const float* prow = p1 + ci * 196 + (r + kr) * 14;
                float xv[10];
                #pragma unroll
                for (int j = 0; j < 10; ++j) xv[j] = prow[j];
                const float* wr = w2s + oc * 150 + ci * 25 + kr * 5;
                float wk[5];
                #pragma unroll
                for (int j = 0; j < 5; ++j) wk[j] = wr[j];
                #pragma unroll
                for (int kc = 0; kc < 5; ++kc)
                    #pragma unroll
                    for (int c = 0; c < 6; ++c)
                        acc[c] += xv[c + kc] * wk[kc];
            }
        }
        #pragma unroll
        for (int c = 0; c < 6; ++c)
            c2[oc * 36 + r * 6 + c] = fmaxf(acc[c], 0.f);
    }
    __syncthreads();

    // ---- stage 4: buggy pool2 -> p2 [16][5][5] = flatten order oc*25+r*5+c ----
    float* p2 = base + BUFB + 576;
    for (int o = lane; o < 400; o += 64) {
        int oc = o / 25, rem = o - oc * 25;
        int r = rem / 5, c = rem - r * 5;
        const float* b0 = c2 + oc * 36 + r * 6 + c;
        p2[o] = fmaxf(fmaxf(b0[0], b0[1]), fmaxf(b0[6], b0[7]));
    }
    __syncthreads();

    // ---- stage 5: fc1 (120 x 400) + relu ----
    float* fc1o = base + BUFB + 976;
    const float4* p2v = (const float4*)p2;
    for (int o = lane; o < 120; o += 64) {
        const float4* wrow = (const float4*)(fc1w + o * 400);
        float acc = fc1b[o];
        for (int k = 0; k < 100; ++k) {
            float4 a = p2v[k], b = wrow[k];
            acc += a.x * b.x + a.y * b.y + a.z * b.z + a.w * b.w;
        }
        fc1o[o] = fmaxf(acc, 0.f);
    }
    __syncthreads();

    // ---- stage 6: fc2 (84 x 120) + relu ----
    float* fc2o = base + BUFB + 1096;
    const float4* f1v = (const float4*)fc1o;
    for (int o = lane; o < 84; o += 64) {
        const float4* wrow = (const float4*)(fc2w + o * 120);
        float acc = fc2b[o];
        for (int k = 0; k < 30; ++k) {
            float4 a = f1v[k], b = wrow[k];
            acc += a.x * b.x + a.y * b.y + a.z * b.z + a.w * b.w;
        }
        fc2o[o] = fmaxf(acc, 0.f);
    }
    __syncthreads();

    // ---- stage 7: fc3 (10 x 84) -> global out ----
    const float4* f2v = (const float4*)fc2o;
    for (int o = lane; o < 10; o += 64) {
        const float4* wrow = (const float4*)(fc3w + o * 84);
        float acc = fc3b[o];
        for (int k = 0; k < 21; ++k) {
            float4 a = f2v[k], b = wrow[k];
            acc += a.x * b.x + a.y * b.y + a.z * b.z + a.w * b.w;
        }
        out[(size_t)img * 10 + o] = acc;
    }
}

extern "C" void kernel_launch(void* const* d_in, const int* in_sizes, int n_in,
                              void* d_out, int out_size, void* d_ws, size_t ws_size,
                              hipStream_t stream) {
    const float* x    = (const float*)d_in[0];
    const float* w1   = (const float*)d_in[1];
    const float* w2   = (const float*)d_in[2];
    const float* fc1w = (const float*)d_in[3];
    const float* fc1b = (const float*)d_in[4];
    const float* fc2w = (const float*)d_in[5];
    const float* fc2b = (const float*)d_in[6];
    const float* fc3w = (const float*)d_in[7];
    const float* fc3b = (const float*)d_in[8];
    float* out = (float*)d_out;

    const int B = in_sizes[0] / 3072;          // 8192
    const int grid = B / IMGS_PER_BLOCK;       // 2048 blocks
    lenet_fused<<<grid, THREADS, 0, stream>>>(x, w1, w2, fc1w, fc1b,
                                              fc2w, fc2b, fc3w, fc3b, out);
}

// Round 2
// 269.940 us; speedup vs baseline: 1.4066x; 1.4066x over previous
//
#include <hip/hip_runtime.h>

// ---------------------------------------------------------------------------
// Fused LeNet forward, round 2.
//  - wave-private stages (conv/pool) sync with s_waitcnt lgkmcnt(0) only:
//    each wave owns one image; 64 lanes are lockstep, so no block barrier.
//  - conv1: lane = (ocpair, row): 45 active lanes, acc[2][15], one pass.
//  - conv2: lane = (ocpair, row): 48 active lanes, acc[2][6], one pass.
//  - FCs are block-cooperative: one weight load feeds 4 per-image accums
//    (cuts fc1_w L2 traffic 4x). Barriers only around the FC section.
//  - LDS rows padded for b128 alignment; total 52880 B -> 3 blocks/CU.
// ---------------------------------------------------------------------------

constexpr int THREADS = 256;
constexpr int IPB = 4;                 // images per block (1 per wave)

// LDS layout (float offsets)
constexpr int W1_OFF = 0;              // conv1 w: 450
constexpr int W2_OFF = 452;            // conv2 w: 2400 (16B-aligned start)
constexpr int IMG_BASE = 2852;
// per-image layout (offsets within image region):
constexpr int XS_OFF = 0;              // [3][19][20] = 1140  (ch=380, row=20)
constexpr int C1_OFF = 1152;           // [6][15][16] = 1440  (oc=240, row=16)
constexpr int P1_OFF = 0;              // [6][14][14] = 1176  (oc=196, row=14) overwrites xs
constexpr int C2_OFF = 1184;           // [16][6][8]  = 768   (oc=48,  row=8)  overwrites c1
constexpr int P2_OFF = 1952;           // [400] flatten order oc*25+r*5+c
constexpr int F1_OFF = 0;              // [120] overwrites p1 (dead)
constexpr int F2_OFF = 128;            // [84]
constexpr int IMG_STRIDE = 2592;       // multiple of 4 (16B-aligned regions)
constexpr int LDS_FLOATS = IMG_BASE + IPB * IMG_STRIDE;   // 13220 -> 52880 B

__device__ __forceinline__ void wave_sync() {
    // all 64 lanes are lockstep; drain LDS ops + compiler memory fence
    asm volatile("s_waitcnt lgkmcnt(0)" ::: "memory");
}

extern "C" __global__ __launch_bounds__(THREADS, 3)
void lenet_fused(const float* __restrict__ x,
                 const float* __restrict__ w1,
                 const float* __restrict__ w2,
                 const float* __restrict__ fc1w, const float* __restrict__ fc1b,
                 const float* __restrict__ fc2w, const float* __restrict__ fc2b,
                 const float* __restrict__ fc3w, const float* __restrict__ fc3b,
                 float* __restrict__ out)
{
    __shared__ __align__(16) float lds[LDS_FLOATS];
    const int tid  = threadIdx.x;
    const int lane = tid & 63;
    const int wv   = tid >> 6;
    const int img0 = blockIdx.x * IPB;

    // ---- stage weights (block-wide, vectorized) ----
    {
        const float4* s1 = (const float4*)w1;
        float4* d1 = (float4*)(lds + W1_OFF);
        for (int i = tid; i < 112; i += THREADS) d1[i] = s1[i];
        if (tid < 2) lds[W1_OFF + 448 + tid] = w1[448 + tid];
        const float4* s2 = (const float4*)w2;
        float4* d2 = (float4*)(lds + W2_OFF);
        for (int i = tid; i < 600; i += THREADS) d2[i] = s2[i];
    }

    // ---- stage input patch rows 0..18, cols 0..19 (per wave, float4) ----
    float* base = lds + IMG_BASE + wv * IMG_STRIDE;
    {
        const float4* xg = (const float4*)(x + (size_t)(img0 + wv) * 3072);
        float4* xs4 = (float4*)(base + XS_OFF);
        for (int i = lane; i < 285; i += 64) {       // 3ch * 19r * 5(f4)
            int c = i / 95, rem = i - c * 95;
            int r = rem / 5, c4 = rem - r * 5;
            xs4[i] = xg[c * 256 + r * 8 + c4];
        }
    }
    __syncthreads();   // weights visible block-wide

    const float* xs  = base + XS_OFF;
    float* c1 = base + C1_OFF;
    const float* w1s = lds + W1_OFF;

    // ---- conv1 + relu -> c1 [6][15][16-pad] ; 45 lanes, 2 oc per lane ----
    if (lane < 45) {
        const int ocp = lane / 15;
        const int r   = lane - ocp * 15;
        const int oc0 = ocp * 2;
        float acc0[15], acc1[15];
        #pragma unroll
        for (int c = 0; c < 15; ++c) { acc0[c] = 0.f; acc1[c] = 0.f; }
        for (int ci = 0; ci < 3; ++ci) {
            #pragma unroll
            for (int kr = 0; kr < 5; ++kr) {
                const float* xrow = xs + ci * 380 + (r + kr) * 20;
                float xv[19];
                #pragma unroll
                for (int j = 0; j < 19; ++j) xv[j] = xrow[j];
                const float* wr0 = w1s + oc0 * 75 + ci * 25 + kr * 5;
                #pragma unroll
                for (int kc = 0; kc < 5; ++kc) {
                    const float wa = wr0[kc];
                    const float wb = wr0[75 + kc];
                    #pragma unroll
                    for (int c = 0; c < 15; ++c) {
                        acc0[c] = fmaf(xv[c + kc], wa, acc0[c]);
                        acc1[c] = fmaf(xv[c + kc], wb, acc1[c]);
                    }
                }
            }
        }
        float* o0 = c1 + oc0 * 240 + r * 16;
        #pragma unroll
        for (int c = 0; c < 15; ++c) {
            o0[c]       = fmaxf(acc0[c], 0.f);
            o0[240 + c] = fmaxf(acc1[c], 0.f);
        }
    }
    wave_sync();

    // ---- buggy pool1 -> p1 [6][14][14] (overwrites xs) ----
    float* p1 = base + P1_OFF;
    for (int o = lane; o < 1176; o += 64) {
        int oc = o / 196, rem = o - oc * 196;
        int r = rem / 14, c = rem - r * 14;
        const float* b0 = c1 + oc * 240 + r * 16 + c;
        p1[o] = fmaxf(fmaxf(b0[0], b0[1]), fmaxf(b0[16], b0[17]));
    }
    wave_sync();

    // ---- conv2 + relu -> c2 [16][6][8-pad] ; 48 lanes, 2 oc per lane ----
    float* c2 = base + C2_OFF;
    const float* w2s = lds + W2_OFF;
    if (lane < 48) {
        const int ocp = lane / 6;
        const int r   = lane - ocp * 6;
        const int oc0 = ocp * 2;
        float acc0[6], acc1[6];
        #pragma unroll
        for (int c = 0; c < 6; ++c) { acc0[c] = 0.f; acc1[c] = 0.f; }
        for (int ci = 0; ci < 6; ++ci) {
            #pragma unroll
            for (int kr = 0; kr < 5; ++kr) {
                const float* prow = p1 + ci * 196 + (r + kr) * 14;
                float xv[10];
                #pragma unroll
                for (int j = 0; j < 10; ++j) xv[j] = prow[j];
                const float* wr0 = w2s + oc0 * 150 + ci * 25 + kr * 5;
                #pragma unroll
                for (int kc = 0; kc < 5; ++kc) {
                    const float wa = wr0[kc];
                    const float wb = wr0[150 + kc];
                    #pragma unroll
                    for (int c = 0; c < 6; ++c) {
                        acc0[c] = fmaf(xv[c + kc], wa, acc0[c]);
                        acc1[c] = fmaf(xv[c + kc], wb, acc1[c]);
                    }
                }
            }
        }
        float* o0 = c2 + oc0 * 48 + r * 8;
        #pragma unroll
        for (int c = 0; c < 6; ++c) {
            o0[c]      = fmaxf(acc0[c], 0.f);
            o0[48 + c] = fmaxf(acc1[c], 0.f);
        }
    }
    wave_sync();

    // ---- buggy pool2 -> p2 [16*5*5] in flatten order ----
    float* p2 = base + P2_OFF;
    for (int o = lane; o < 400; o += 64) {
        int oc = o / 25, rem = o - oc * 25;
        int r = rem / 5, c = rem - r * 5;
        const float* b0 = c2 + oc * 48 + r * 8 + c;
        p2[o] = fmaxf(fmaxf(b0[0], b0[1]), fmaxf(b0[8], b0[9]));
    }
    __syncthreads();   // all 4 images' p2 ready -> block-cooperative FCs

    // ---- fc1 (120x400) + relu : thread=row, one w load feeds 4 images ----
    if (tid < 120) {
        const int row = tid;
        const float4* wrow = (const float4*)(fc1w + row * 400);
        const float bz = fc1b[row];
        float acc0 = bz, acc1 = bz, acc2 = bz, acc3 = bz;
        const float4* p0 = (const float4*)(lds + IMG_BASE + 0 * IMG_STRIDE + P2_OFF);
        const float4* p1v = (const float4*)(lds + IMG_BASE + 1 * IMG_STRIDE + P2_OFF);
        const float4* p2v = (const float4*)(lds + IMG_BASE + 2 * IMG_STRIDE + P2_OFF);
        const float4* p3v = (const float4*)(lds + IMG_BASE + 3 * IMG_STRIDE + P2_OFF);
        #pragma unroll 2
        for (int k = 0; k < 100; ++k) {
            float4 w4 = wrow[k];
            float4 a0 = p0[k], a1 = p1v[k], a2 = p2v[k], a3 = p3v[k];
            acc0 = fmaf(a0.x, w4.x, acc0); acc0 = fmaf(a0.y, w4.y, acc0);
            acc0 = fmaf(a0.z, w4.z, acc0); acc0 = fmaf(a0.w, w4.w, acc0);
            acc1 = fmaf(a1.x, w4.x, acc1); acc1 = fmaf(a1.y, w4.y, acc1);
            acc1 = fmaf(a1.z, w4.z, acc1); acc1 = fmaf(a1.w, w4.w, acc1);
            acc2 = fmaf(a2.x, w4.x, acc2); acc2 = fmaf(a2.y, w4.y, acc2);
            acc2 = fmaf(a2.z, w4.z, acc2); acc2 = fmaf(a2.w, w4.w, acc2);
            acc3 = fmaf(a3.x, w4.x, acc3); acc3 = fmaf(a3.y, w4.y, acc3);
            acc3 = fmaf(a3.z, w4.z, acc3); acc3 = fmaf(a3.w, w4.w, acc3);
        }
        lds[IMG_BASE + 0 * IMG_STRIDE + F1_OFF + row] = fmaxf(acc0, 0.f);
        lds[IMG_BASE + 1 * IMG_STRIDE + F1_OFF + row] = fmaxf(acc1, 0.f);
        lds[IMG_BASE + 2 * IMG_STRIDE + F1_OFF + row] = fmaxf(acc2, 0.f);
        lds[IMG_BASE + 3 * IMG_STRIDE + F1_OFF + row] = fmaxf(acc3, 0.f);
    }
    __syncthreads();

    // ---- fc2 (84x120) + relu ----
    if (tid < 84) {
        const int row = tid;
        const float4* wrow = (const float4*)(fc2w + row * 120);
        const float bz = fc2b[row];
        float acc0 = bz, acc1 = bz, acc2 = bz, acc3 = bz;
        const float4* f0 = (const float4*)(lds + IMG_BASE + 0 * IMG_STRIDE + F1_OFF);
        const float4* f1 = (const float4*)(lds + IMG_BASE + 1 * IMG_STRIDE + F1_OFF);
        const float4* f2 = (const float4*)(lds + IMG_BASE + 2 * IMG_STRIDE + F1_OFF);
        const float4* f3 = (const float4*)(lds + IMG_BASE + 3 * IMG_STRIDE + F1_OFF);
        #pragma unroll 2
        for (int k = 0; k < 30; ++k) {
            float4 w4 = wrow[k];
            float4 a0 = f0[k], a1 = f1[k], a2 = f2[k], a3 = f3[k];
            acc0 = fmaf(a0.x, w4.x, acc0); acc0 = fmaf(a0.y, w4.y, acc0);
            acc0 = fmaf(a0.z, w4.z, acc0); acc0 = fmaf(a0.w, w4.w, acc0);
            acc1 = fmaf(a1.x, w4.x, acc1); acc1 = fmaf(a1.y, w4.y, acc1);
            acc1 = fmaf(a1.z, w4.z, acc1); acc1 = fmaf(a1.w, w4.w, acc1);
            acc2 = fmaf(a2.x, w4.x, acc2); acc2 = fmaf(a2.y, w4.y, acc2);
            acc2 = fmaf(a2.z, w4.z, acc2); acc2 = fmaf(a2.w, w4.w, acc2);
            acc3 = fmaf(a3.x, w4.x, acc3); acc3 = fmaf(a3.y, w4.y, acc3);
            acc3 = fmaf(a3.z, w4.z, acc3); acc3 = fmaf(a3.w, w4.w, acc3);
        }
        lds[IMG_BASE + 0 * IMG_STRIDE + F2_OFF + row] = fmaxf(acc0, 0.f);
        lds[IMG_BASE + 1 * IMG_STRIDE + F2_OFF + row] = fmaxf(acc1, 0.f);
        lds[IMG_BASE + 2 * IMG_STRIDE + F2_OFF + row] = fmaxf(acc2, 0.f);
        lds[IMG_BASE + 3 * IMG_STRIDE + F2_OFF + row] = fmaxf(acc3, 0.f);
    }
    __syncthreads();

    // ---- fc3 (10x84) -> out ----
    if (tid < 40) {
        const int im  = tid / 10;
        const int row = tid - im * 10;
        const float4* wrow = (const float4*)(fc3w + row * 84);
        const float4* f2 = (const float4*)(lds + IMG_BASE + im * IMG_STRIDE + F2_OFF);
        float acc = fc3b[row];
        #pragma unroll
        for (int k = 0; k < 21; ++k) {
            float4 w4 = wrow[k];
            float4 a = f2[k];
            acc = fmaf(a.x, w4.x, acc); acc = fmaf(a.y, w4.y, acc);
            acc = fmaf(a.z, w4.z, acc); acc = fmaf(a.w, w4.w, acc);
        }
        out[(size_t)(img0 + im) * 10 + row] = acc;
    }
}

extern "C" void kernel_launch(void* const* d_in, const int* in_sizes, int n_in,
                              void* d_out, int out_size, void* d_ws, size_t ws_size,
                              hipStream_t stream) {
    const float* x    = (const float*)d_in[0];
    const float* w1   = (const float*)d_in[1];
    const float* w2   = (const float*)d_in[2];
    const float* fc1w = (const float*)d_in[3];
    const float* fc1b = (const float*)d_in[4];
    const float* fc2w = (const float*)d_in[5];
    const float* fc2b = (const float*)d_in[6];
    const float* fc3w = (const float*)d_in[7];
    const float* fc3b = (const float*)d_in[8];
    float* out = (float*)d_out;

    const int B = in_sizes[0] / 3072;       // 8192
    const int grid = B / IPB;               // 2048
    lenet_fused<<<grid, THREADS, 0, stream>>>(x, w1, w2, fc1w, fc1b,
                                              fc2w, fc2b, fc3w, fc3b, out);
}

// Round 3
// 246.081 us; speedup vs baseline: 1.5430x; 1.0970x over previous
//
#include <hip/hip_runtime.h>

// ---------------------------------------------------------------------------
// Fused LeNet forward, round 3.
//  - conv1+relu+pool1 fused in registers: lane r holds conv row r; row r+1
//    obtained via __shfl(lane+1) (pairwise col-max first). c1 never hits LDS.
//  - conv2+relu+pool2 fused the same way. c2 never hits LDS.
//  - per-image LDS: union(xs 1140, p1 1176) + p2 400 + f1/f2 -> 1600 floats.
//    Total 37 KB -> 4 blocks/CU (16 waves/CU), launch_bounds(256,4).
//  - fc1 K-split x2: 240 threads compute half-rows; partials reduced via the
//    dead conv2-weight LDS region.
// ---------------------------------------------------------------------------

constexpr int THREADS = 256;
constexpr int IPB = 4;                 // images per block (1 per wave)

// LDS layout (float offsets)
constexpr int W1_OFF = 0;              // conv1 w: 450
constexpr int W2_OFF = 452;            // conv2 w: 2400; reused as FC1 scratch
constexpr int IMG_BASE = 2852;
// per-image offsets:
constexpr int XS_OFF = 0;              // [3][19][20] = 1140
constexpr int P1_OFF = 0;              // [6][14][14] = 1176 (overwrites xs)
constexpr int P2_OFF = 1184;           // [400] flatten order oc*25+r*5+c
constexpr int F1_OFF = 0;              // [120] (overwrites p1, dead after conv2)
constexpr int F2_OFF = 128;            // [84]
constexpr int IMG_STRIDE = 1600;
constexpr int LDS_FLOATS = IMG_BASE + IPB * IMG_STRIDE;   // 9252 -> 37008 B

__device__ __forceinline__ void wave_sync() {
    asm volatile("s_waitcnt lgkmcnt(0)" ::: "memory");
}

extern "C" __global__ __launch_bounds__(THREADS, 4)
void lenet_fused(const float* __restrict__ x,
                 const float* __restrict__ w1,
                 const float* __restrict__ w2,
                 const float* __restrict__ fc1w, const float* __restrict__ fc1b,
                 const float* __restrict__ fc2w, const float* __restrict__ fc2b,
                 const float* __restrict__ fc3w, const float* __restrict__ fc3b,
                 float* __restrict__ out)
{
    __shared__ __align__(16) float lds[LDS_FLOATS];
    const int tid  = threadIdx.x;
    const int lane = tid & 63;
    const int wv   = tid >> 6;
    const int img0 = blockIdx.x * IPB;

    // ---- stage weights (block-wide, float4) ----
    {
        const float4* s1 = (const float4*)w1;
        float4* d1 = (float4*)(lds + W1_OFF);
        for (int i = tid; i < 112; i += THREADS) d1[i] = s1[i];
        if (tid < 2) lds[W1_OFF + 448 + tid] = w1[448 + tid];
        const float4* s2 = (const float4*)w2;
        float4* d2 = (float4*)(lds + W2_OFF);
        for (int i = tid; i < 600; i += THREADS) d2[i] = s2[i];
    }

    // ---- stage input patch rows 0..18, cols 0..19 (per wave, float4) ----
    float* base = lds + IMG_BASE + wv * IMG_STRIDE;
    {
        const float4* xg = (const float4*)(x + (size_t)(img0 + wv) * 3072);
        float4* xs4 = (float4*)(base + XS_OFF);
        for (int i = lane; i < 285; i += 64) {       // 3ch * 19r * 5(f4)
            int c = i / 95, rem = i - c * 95;
            int r = rem / 5, c4 = rem - r * 5;
            xs4[i] = xg[c * 256 + r * 8 + c4];
        }
    }
    __syncthreads();

    const float* xs  = base + XS_OFF;
    const float* w1s = lds + W1_OFF;
    float* p1 = base + P1_OFF;

    // ---- conv1 + relu + pool1 -> p1 [6][14][14] ----
    // lane -> (ocpair 0..2, row 0..14); lanes 45..63 duplicate lane 44 so all
    // 64 lanes execute the shfls (sources must be active).
    {
        const int l   = (lane < 45) ? lane : 44;
        const int ocp = l / 15;
        const int r   = l - ocp * 15;
        const int oc0 = ocp * 2;
        float acc0[15], acc1[15];
        #pragma unroll
        for (int c = 0; c < 15; ++c) { acc0[c] = 0.f; acc1[c] = 0.f; }
        for (int ci = 0; ci < 3; ++ci) {
            #pragma unroll
            for (int kr = 0; kr < 5; ++kr) {
                const float* xrow = xs + ci * 380 + (r + kr) * 20;
                float xv[19];
                #pragma unroll
                for (int j = 0; j < 19; ++j) xv[j] = xrow[j];
                const float* wr0 = w1s + oc0 * 75 + ci * 25 + kr * 5;
                #pragma unroll
                for (int kc = 0; kc < 5; ++kc) {
                    const float wa = wr0[kc];
                    const float wb = wr0[75 + kc];
                    #pragma unroll
                    for (int c = 0; c < 15; ++c) {
                        acc0[c] = fmaf(xv[c + kc], wa, acc0[c]);
                        acc1[c] = fmaf(xv[c + kc], wb, acc1[c]);
                    }
                }
            }
        }
        // relu + pairwise col max (14 per oc)
        float pm0[14], pm1[14];
        #pragma unroll
        for (int c = 0; c < 14; ++c) {
            float a = fmaxf(acc0[c], 0.f), b = fmaxf(acc0[c + 1], 0.f);
            pm0[c] = fmaxf(a, b);
            float e = fmaxf(acc1[c], 0.f), f = fmaxf(acc1[c + 1], 0.f);
            pm1[c] = fmaxf(e, f);
        }
        // neighbor row's pairwise max via shfl (all 64 lanes execute)
        float m0[14], m1[14];
        #pragma unroll
        for (int c = 0; c < 14; ++c) {
            m0[c] = fmaxf(pm0[c], __shfl(pm0[c], lane + 1, 64));
            m1[c] = fmaxf(pm1[c], __shfl(pm1[c], lane + 1, 64));
        }
        wave_sync();   // drain xs reads before overwriting region with p1
        if (r < 14) {  // lanes 45..63 have r==14 -> excluded
            float2* d0 = (float2*)(p1 + oc0 * 196 + r * 14);
            float2* d1 = (float2*)(p1 + (oc0 + 1) * 196 + r * 14);
            #pragma unroll
            for (int j = 0; j < 7; ++j) {
                d0[j] = make_float2(m0[2 * j], m0[2 * j + 1]);
                d1[j] = make_float2(m1[2 * j], m1[2 * j + 1]);
            }
        }
    }
    wave_sync();

    // ---- conv2 + relu + pool2 -> p2 [16*5*5] flatten order ----
    float* p2 = base + P2_OFF;
    const float* w2s = lds + W2_OFF;
    {
        const int l   = (lane < 48) ? lane : 47;
        const int ocp = l / 6;
        const int r   = l - ocp * 6;
        const int oc0 = ocp * 2;
        float acc0[6], acc1[6];
        #pragma unroll
        for (int c = 0; c < 6; ++c) { acc0[c] = 0.f; acc1[c] = 0.f; }
        for (int ci = 0; ci < 6; ++ci) {
            #pragma unroll
            for (int kr = 0; kr < 5; ++kr) {
                const float* prow = p1 + ci * 196 + (r + kr) * 14;
                float xv[10];
                #pragma unroll
                for (int j = 0; j < 10; ++j) xv[j] = prow[j];
                const float* wr0 = w2s + oc0 * 150 + ci * 25 + kr * 5;
                #pragma unroll
                for (int kc = 0; kc < 5; ++kc) {
                    const float wa = wr0[kc];
                    const float wb = wr0[150 + kc];
                    #pragma unroll
                    for (int c = 0; c < 6; ++c) {
                        acc0[c] = fmaf(xv[c + kc], wa, acc0[c]);
                        acc1[c] = fmaf(xv[c + kc], wb, acc1[c]);
                    }
                }
            }
        }
        float pm0[5], pm1[5];
        #pragma unroll
        for (int c = 0; c < 5; ++c) {
            float a = fmaxf(acc0[c], 0.f), b = fmaxf(acc0[c + 1], 0.f);
            pm0[c] = fmaxf(a, b);
            float e = fmaxf(acc1[c], 0.f), f = fmaxf(acc1[c + 1], 0.f);
            pm1[c] = fmaxf(e, f);
        }
        float m0[5], m1[5];
        #pragma unroll
        for (int c = 0; c < 5; ++c) {
            m0[c] = fmaxf(pm0[c], __shfl(pm0[c], lane + 1, 64));
            m1[c] = fmaxf(pm1[c], __shfl(pm1[c], lane + 1, 64));
        }
        if (r < 5) {   // lanes 48..63 have r==5 -> excluded
            float* q0 = p2 + oc0 * 25 + r * 5;
            float* q1 = p2 + (oc0 + 1) * 25 + r * 5;
            #pragma unroll
            for (int c = 0; c < 5; ++c) { q0[c] = m0[c]; q1[c] = m1[c]; }
        }
    }
    __syncthreads();   // all images' p2 ready; w2 region becomes FC scratch

    // ---- fc1 (120x400) K-split x2: 240 threads, partials -> scratch ----
    float* scr = lds + W2_OFF;   // 960 floats
    if (tid < 240) {
        const int row  = tid >> 1;
        const int half = tid & 1;
        const float4* wrow = (const float4*)(fc1w + row * 400) + half * 50;
        const float4* a0p = (const float4*)(lds + IMG_BASE + 0 * IMG_STRIDE + P2_OFF) + half * 50;
        const float4* a1p = (const float4*)(lds + IMG_BASE + 1 * IMG_STRIDE + P2_OFF) + half * 50;
        const float4* a2p = (const float4*)(lds + IMG_BASE + 2 * IMG_STRIDE + P2_OFF) + half * 50;
        const float4* a3p = (const float4*)(lds + IMG_BASE + 3 * IMG_STRIDE + P2_OFF) + half * 50;
        float acc0 = 0.f, acc1 = 0.f, acc2 = 0.f, acc3 = 0.f;
        #pragma unroll 2
        for (int k = 0; k < 50; ++k) {
            float4 w4 = wrow[k];
            float4 a0 = a0p[k], a1 = a1p[k], a2 = a2p[k], a3 = a3p[k];
            acc0 = fmaf(a0.x, w4.x, acc0); acc0 = fmaf(a0.y, w4.y, acc0);
            acc0 = fmaf(a0.z, w4.z, acc0); acc0 = fmaf(a0.w, w4.w, acc0);
            acc1 = fmaf(a1.x, w4.x, acc1); acc1 = fmaf(a1.y, w4.y, acc1);
            acc1 = fmaf(a1.z, w4.z, acc1); acc1 = fmaf(a1.w, w4.w, acc1);
            acc2 = fmaf(a2.x, w4.x, acc2); acc2 = fmaf(a2.y, w4.y, acc2);
            acc2 = fmaf(a2.z, w4.z, acc2); acc2 = fmaf(a2.w, w4.w, acc2);
            acc3 = fmaf(a3.x, w4.x, acc3); acc3 = fmaf(a3.y, w4.y, acc3);
            acc3 = fmaf(a3.z, w4.z, acc3); acc3 = fmaf(a3.w, w4.w, acc3);
        }
        scr[0 * 240 + row * 2 + half] = acc0;
        scr[1 * 240 + row * 2 + half] = acc1;
        scr[2 * 240 + row * 2 + half] = acc2;
        scr[3 * 240 + row * 2 + half] = acc3;
    }
    __syncthreads();

    // ---- fc1 reduce + bias + relu -> f1 per image ----
    if (tid < 120) {
        const float b = fc1b[tid];
        #pragma unroll
        for (int im = 0; im < 4; ++im) {
            float v = scr[im * 240 + tid * 2] + scr[im * 240 + tid * 2 + 1] + b;
            lds[IMG_BASE + im * IMG_STRIDE + F1_OFF + tid] = fmaxf(v, 0.f);
        }
    }
    __syncthreads();

    // ---- fc2 (84x120) + relu ----
    if (tid < 84) {
        const int row = tid;
        const float4* wrow = (const float4*)(fc2w + row * 120);
        const float bz = fc2b[row];
        float acc0 = bz, acc1 = bz, acc2 = bz, acc3 = bz;
        const float4* f0 = (const float4*)(lds + IMG_BASE + 0 * IMG_STRIDE + F1_OFF);
        const float4* f1 = (const float4*)(lds + IMG_BASE + 1 * IMG_STRIDE + F1_OFF);
        const float4* f2 = (const float4*)(lds + IMG_BASE + 2 * IMG_STRIDE + F1_OFF);
        const float4* f3 = (const float4*)(lds + IMG_BASE + 3 * IMG_STRIDE + F1_OFF);
        #pragma unroll 2
        for (int k = 0; k < 30; ++k) {
            float4 w4 = wrow[k];
            float4 a0 = f0[k], a1 = f1[k], a2 = f2[k], a3 = f3[k];
            acc0 = fmaf(a0.x, w4.x, acc0); acc0 = fmaf(a0.y, w4.y, acc0);
            acc0 = fmaf(a0.z, w4.z, acc0); acc0 = fmaf(a0.w, w4.w, acc0);
            acc1 = fmaf(a1.x, w4.x, acc1); acc1 = fmaf(a1.y, w4.y, acc1);
            acc1 = fmaf(a1.z, w4.z, acc1); acc1 = fmaf(a1.w, w4.w, acc1);
            acc2 = fmaf(a2.x, w4.x, acc2); acc2 = fmaf(a2.y, w4.y, acc2);
            acc2 = fmaf(a2.z, w4.z, acc2); acc2 = fmaf(a2.w, w4.w, acc2);
            acc3 = fmaf(a3.x, w4.x, acc3); acc3 = fmaf(a3.y, w4.y, acc3);
            acc3 = fmaf(a3.z, w4.z, acc3); acc3 = fmaf(a3.w, w4.w, acc3);
        }
        lds[IMG_BASE + 0 * IMG_STRIDE + F2_OFF + row] = fmaxf(acc0, 0.f);
        lds[IMG_BASE + 1 * IMG_STRIDE + F2_OFF + row] = fmaxf(acc1, 0.f);
        lds[IMG_BASE + 2 * IMG_STRIDE + F2_OFF + row] = fmaxf(acc2, 0.f);
        lds[IMG_BASE + 3 * IMG_STRIDE + F2_OFF + row] = fmaxf(acc3, 0.f);
    }
    __syncthreads();

    // ---- fc3 (10x84) -> out ----
    if (tid < 40) {
        const int im  = tid / 10;
        const int row = tid - im * 10;
        const float4* wrow = (const float4*)(fc3w + row * 84);
        const float4* f2 = (const float4*)(lds + IMG_BASE + im * IMG_STRIDE + F2_OFF);
        float acc = fc3b[row];
        #pragma unroll
        for (int k = 0; k < 21; ++k) {
            float4 w4 = wrow[k];
            float4 a = f2[k];
            acc = fmaf(a.x, w4.x, acc); acc = fmaf(a.y, w4.y, acc);
            acc = fmaf(a.z, w4.z, acc); acc = fmaf(a.w, w4.w, acc);
        }
        out[(size_t)(img0 + im) * 10 + row] = acc;
    }
}

extern "C" void kernel_launch(void* const* d_in, const int* in_sizes, int n_in,
                              void* d_out, int out_size, void* d_ws, size_t ws_size,
                              hipStream_t stream) {
    const float* x    = (const float*)d_in[0];
    const float* w1   = (const float*)d_in[1];
    const float* w2   = (const float*)d_in[2];
    const float* fc1w = (const float*)d_in[3];
    const float* fc1b = (const float*)d_in[4];
    const float* fc2w = (const float*)d_in[5];
    const float* fc2b = (const float*)d_in[6];
    const float* fc3w = (const float*)d_in[7];
    const float* fc3b = (const float*)d_in[8];
    float* out = (float*)d_out;

    const int B = in_sizes[0] / 3072;       // 8192
    const int grid = B / IPB;               // 2048
    lenet_fused<<<grid, THREADS, 0, stream>>>(x, w1, w2, fc1w, fc1b,
                                              fc2w, fc2b, fc3w, fc3b, out);
}